// Round 3
// baseline (407.357 us; speedup 1.0000x reference)
//
#include <hip/hip_runtime.h>
#include <math.h>

#define EPS 1e-8f

typedef float vfloat4 __attribute__((ext_vector_type(4)));

// ---------------- prep kernel (fused transpose + Gram) ----------------
// blocks 0..383   : transpose W_enc [24][1024] -> wt [1024][24]  (64 thr each)
// blocks 384..959 : G[l][m] = sum_d Wd[d][l]*Wd[d][m]
// blocks 960..983 : h[l] = sum_d Wd[d][l]*bd[d]
// block  984      : bb = ||bd||^2
__global__ void prep_all(const float* __restrict__ W_enc,
                         const float* __restrict__ Wd, const float* __restrict__ bd,
                         float* __restrict__ wt, float* __restrict__ G,
                         float* __restrict__ h, float* __restrict__ bb) {
    int b = blockIdx.x;
    int lane = threadIdx.x;     // 64
    if (b < 384) {
        int i = b * 64 + lane;  // 0..24575
        int k = i / 24, l = i - k * 24;
        wt[i] = W_enc[l * 1024 + k];
        return;
    }
    b -= 384;
    float s = 0.f;
    if (b < 576) {
        int l = b / 24, m = b - (b / 24) * 24;
        for (int d = lane; d < 1024; d += 64) s = fmaf(Wd[d * 24 + l], Wd[d * 24 + m], s);
    } else if (b < 600) {
        int l = b - 576;
        for (int d = lane; d < 1024; d += 64) s = fmaf(Wd[d * 24 + l], bd[d], s);
    } else {
        for (int d = lane; d < 1024; d += 64) s = fmaf(bd[d], bd[d], s);
    }
    for (int off = 32; off; off >>= 1) s += __shfl_down(s, off);
    if (lane == 0) {
        if (b < 576) G[b] = s;
        else if (b < 600) h[b - 576] = s;
        else *bb = s;
    }
}

// ---------------- main kernel ----------------
// Block = 512 threads (8 waves), 64 rows per block, lane = row.
// Wave w owns k-range [128w,128w+128) (encode) and same d-range (decode).
// KEY CHANGE (r3): weight reads in the hot loops go through VMEM
// (global_load_dwordx4, vmcnt) instead of s_load (lgkmcnt). Rationale:
// s_load + ds_read mixed in flight share lgkmcnt and retire out of order,
// forcing conservative lgkmcnt(0) waits every iteration; plus 192 KB/block
// of weight traffic thrashes the tiny shared scalar K$. The +zz
// (threadIdx.y, runtime 0 but not provably uniform) forces the vector path;
// uniform addresses broadcast from L1/L2 lines.

constexpr int LD_TILE = 32;            // XOR-swizzled, no pad
constexpr int TILE_F  = 64 * LD_TILE;  // 2048 floats per wave
constexpr int NW      = 8;
constexpr int SMEM_F  = NW * TILE_F;   // 16384 floats = 65536 B -> 2 blocks/CU

__global__ __launch_bounds__(512, 4)
void leech_main(const float* __restrict__ data,
                const float* __restrict__ b_enc,
                const float* __restrict__ Wd,
                const float* __restrict__ b_dec,
                const float* __restrict__ ecs_p,
                const float* __restrict__ ep_p,
                const float* __restrict__ wt,
                const float* __restrict__ G,
                const float* __restrict__ h,
                const float* __restrict__ bbp,
                float* __restrict__ out)
{
    __shared__ float smem[SMEM_F];
    const int tid = threadIdx.x;
    const int zz = threadIdx.y;     // runtime 0; defeats scalarization of weight loads
    const int w = tid >> 6;         // 0..7
    const int r = tid & 63;
    const int rowbase = blockIdx.x * 64;

    float* tile = smem + w * TILE_F;

    const int lrow = r >> 3;        // 0..7
    const int lk   = (r & 7) * 4;   // 0,4,...,28

    // -------- encode: proj partials over this wave's 128-wide k-range --------
    float proj[24];
#pragma unroll
    for (int l = 0; l < 24; ++l) proj[l] = 0.f;
    float ssq = 0.f;

    const int kw = __builtin_amdgcn_readfirstlane((tid >> 6) * 128);

    float4 buf[8];
#pragma unroll
    for (int it = 0; it < 8; ++it)
        buf[it] = *reinterpret_cast<const float4*>(
            data + (size_t)(rowbase + it * 8 + lrow) * 1024 + kw + lk);

    for (int sc = 0; sc < 4; ++sc) {
        // stage current chunk into wave-private swizzled tile
#pragma unroll
        for (int it = 0; it < 8; ++it) {
            const int row = it * 8 + lrow;
            const int rb = row & 31;
            float* t = tile + row * LD_TILE;
            t[(lk + 0) ^ rb] = buf[it].x;
            t[(lk + 1) ^ rb] = buf[it].y;
            t[(lk + 2) ^ rb] = buf[it].z;
            t[(lk + 3) ^ rb] = buf[it].w;
        }
        // prefetch next chunk (issued before compute; latency hidden)
        if (sc < 3) {
            const int k0n = kw + (sc + 1) * 32;
#pragma unroll
            for (int it = 0; it < 8; ++it)
                buf[it] = *reinterpret_cast<const float4*>(
                    data + (size_t)(rowbase + it * 8 + lrow) * 1024 + k0n + lk);
        }
        // compute on current chunk (same-wave LDS in-order: no barrier)
        const float* xrow = tile + r * LD_TILE;
        const int rb = r & 31;
        const int kofs = __builtin_amdgcn_readfirstlane(kw + sc * 32);
#pragma unroll 4
        for (int kk = 0; kk < 32; ++kk) {
            const float x = xrow[kk ^ rb];
            ssq = fmaf(x, x, ssq);
            // VMEM weight broadcast (per-lane addr via zz; 6x dwordx4, imm offsets)
            const float* wp = wt + (size_t)((kofs + kk) * 24) + zz;
            const vfloat4 w0 = *reinterpret_cast<const vfloat4*>(wp);
            const vfloat4 w1 = *reinterpret_cast<const vfloat4*>(wp + 4);
            const vfloat4 w2 = *reinterpret_cast<const vfloat4*>(wp + 8);
            const vfloat4 w3 = *reinterpret_cast<const vfloat4*>(wp + 12);
            const vfloat4 w4 = *reinterpret_cast<const vfloat4*>(wp + 16);
            const vfloat4 w5 = *reinterpret_cast<const vfloat4*>(wp + 20);
            proj[ 0] = fmaf(w0.x, x, proj[ 0]);
            proj[ 1] = fmaf(w0.y, x, proj[ 1]);
            proj[ 2] = fmaf(w0.z, x, proj[ 2]);
            proj[ 3] = fmaf(w0.w, x, proj[ 3]);
            proj[ 4] = fmaf(w1.x, x, proj[ 4]);
            proj[ 5] = fmaf(w1.y, x, proj[ 5]);
            proj[ 6] = fmaf(w1.z, x, proj[ 6]);
            proj[ 7] = fmaf(w1.w, x, proj[ 7]);
            proj[ 8] = fmaf(w2.x, x, proj[ 8]);
            proj[ 9] = fmaf(w2.y, x, proj[ 9]);
            proj[10] = fmaf(w2.z, x, proj[10]);
            proj[11] = fmaf(w2.w, x, proj[11]);
            proj[12] = fmaf(w3.x, x, proj[12]);
            proj[13] = fmaf(w3.y, x, proj[13]);
            proj[14] = fmaf(w3.z, x, proj[14]);
            proj[15] = fmaf(w3.w, x, proj[15]);
            proj[16] = fmaf(w4.x, x, proj[16]);
            proj[17] = fmaf(w4.y, x, proj[17]);
            proj[18] = fmaf(w4.z, x, proj[18]);
            proj[19] = fmaf(w4.w, x, proj[19]);
            proj[20] = fmaf(w5.x, x, proj[20]);
            proj[21] = fmaf(w5.y, x, proj[21]);
            proj[22] = fmaf(w5.z, x, proj[22]);
            proj[23] = fmaf(w5.w, x, proj[23]);
        }
    }

    // -------- combine partials across the 8 waves (overlay own tile) --------
#pragma unroll
    for (int l = 0; l < 24; ++l)
        smem[w * TILE_F + l * 64 + r] = proj[l];
    smem[w * TILE_F + 24 * 64 + r] = ssq;
    __syncthreads();

    float p[24];
#pragma unroll
    for (int l = 0; l < 24; ++l) {
        float s0 = smem[0 * TILE_F + l * 64 + r] + smem[1 * TILE_F + l * 64 + r];
        float s1 = smem[2 * TILE_F + l * 64 + r] + smem[3 * TILE_F + l * 64 + r];
        float s2 = smem[4 * TILE_F + l * 64 + r] + smem[5 * TILE_F + l * 64 + r];
        float s3 = smem[6 * TILE_F + l * 64 + r] + smem[7 * TILE_F + l * 64 + r];
        p[l] = (s0 + s1) + (s2 + s3);
    }
    float ss;
    {
        float s0 = smem[0 * TILE_F + 24 * 64 + r] + smem[1 * TILE_F + 24 * 64 + r];
        float s1 = smem[2 * TILE_F + 24 * 64 + r] + smem[3 * TILE_F + 24 * 64 + r];
        float s2 = smem[4 * TILE_F + 24 * 64 + r] + smem[5 * TILE_F + 24 * 64 + r];
        float s3 = smem[6 * TILE_F + 24 * 64 + r] + smem[7 * TILE_F + 24 * 64 + r];
        ss = (s0 + s1) + (s2 + s3);
    }
    __syncthreads();   // all combine reads done before decode overwrites tiles

    // -------- per-row epilogue --------
    const float ecs = ecs_p[0];
    const float ep  = ep_p[0];
    const float in_e = sqrtf(ss);

    float lp[24]; float oe = 0.f;
#pragma unroll
    for (int l = 0; l < 24; ++l) {
        const float pp = p[l] + b_enc[l];
        const float q = rintf(pp / ecs) * ecs;   // half-even, exact div to match np
        lp[l] = q;
        oe = fmaf(q, q, oe);
    }
    const float s1 = in_e / (sqrtf(oe) + EPS) * ep;

    float c[24]; float ie = 0.f;
#pragma unroll
    for (int l = 0; l < 24; ++l) {
        const float lat = lp[l] * s1;
        ie = fmaf(lat, lat, ie);
        c[l] = (fabsf(lat) > ecs) ? lat : 0.f;
    }
    const float in_e2 = sqrtf(ie);

    // ||Wd c + b_dec||^2 = c^T G c + 2 h^T c + bb
    float qacc = bbp[0];
#pragma unroll
    for (int l = 0; l < 24; ++l) {
        float s = 2.f * h[l];
#pragma unroll
        for (int m = 0; m < 24; ++m)
            s = fmaf(G[l * 24 + m], c[m], s);
        qacc = fmaf(s, c[l], qacc);
    }
    const float out_e2 = sqrtf(fmaxf(qacc, 0.f));
    const float s2 = in_e2 / (out_e2 + EPS) * ep;

    // -------- decode: wave-private swizzled transpose tiles, no barriers ----
    for (int sc = 0; sc < 4; ++sc) {
        const int d0 = __builtin_amdgcn_readfirstlane(kw + sc * 32);
        float* trow = tile + r * LD_TILE;
        const int rb = r & 31;
#pragma unroll 4
        for (int dd = 0; dd < 32; ++dd) {
            const int d = d0 + dd;
            // VMEM weight broadcast (per-lane addr via zz)
            const float* wr = Wd + (size_t)(d * 24) + zz;
            const vfloat4 w0 = *reinterpret_cast<const vfloat4*>(wr);
            const vfloat4 w1 = *reinterpret_cast<const vfloat4*>(wr + 4);
            const vfloat4 w2 = *reinterpret_cast<const vfloat4*>(wr + 8);
            const vfloat4 w3 = *reinterpret_cast<const vfloat4*>(wr + 12);
            const vfloat4 w4 = *reinterpret_cast<const vfloat4*>(wr + 16);
            const vfloat4 w5 = *reinterpret_cast<const vfloat4*>(wr + 20);
            float acc = b_dec[d + zz];
            acc = fmaf(w0.x, c[ 0], acc);
            acc = fmaf(w0.y, c[ 1], acc);
            acc = fmaf(w0.z, c[ 2], acc);
            acc = fmaf(w0.w, c[ 3], acc);
            acc = fmaf(w1.x, c[ 4], acc);
            acc = fmaf(w1.y, c[ 5], acc);
            acc = fmaf(w1.z, c[ 6], acc);
            acc = fmaf(w1.w, c[ 7], acc);
            acc = fmaf(w2.x, c[ 8], acc);
            acc = fmaf(w2.y, c[ 9], acc);
            acc = fmaf(w2.z, c[10], acc);
            acc = fmaf(w2.w, c[11], acc);
            acc = fmaf(w3.x, c[12], acc);
            acc = fmaf(w3.y, c[13], acc);
            acc = fmaf(w3.z, c[14], acc);
            acc = fmaf(w3.w, c[15], acc);
            acc = fmaf(w4.x, c[16], acc);
            acc = fmaf(w4.y, c[17], acc);
            acc = fmaf(w4.z, c[18], acc);
            acc = fmaf(w4.w, c[19], acc);
            acc = fmaf(w5.x, c[20], acc);
            acc = fmaf(w5.y, c[21], acc);
            acc = fmaf(w5.z, c[22], acc);
            acc = fmaf(w5.w, c[23], acc);
            trow[dd ^ rb] = acc * s2;
        }
        // same-wave LDS in-order: reads below see this wave's writes above
#pragma unroll
        for (int it = 0; it < 8; ++it) {
            const int row = it * 8 + lrow;
            const int rb2 = row & 31;
            const float* t = tile + row * LD_TILE;
            vfloat4 v;
            v.x = t[(lk + 0) ^ rb2];
            v.y = t[(lk + 1) ^ rb2];
            v.z = t[(lk + 2) ^ rb2];
            v.w = t[(lk + 3) ^ rb2];
            __builtin_nontemporal_store(v, reinterpret_cast<vfloat4*>(
                out + (size_t)(rowbase + row) * 1024 + d0 + lk));
        }
    }
}

// ---------------- launcher ----------------

extern "C" void kernel_launch(void* const* d_in, const int* in_sizes, int n_in,
                              void* d_out, int out_size, void* d_ws, size_t ws_size,
                              hipStream_t stream) {
    const float* data  = (const float*)d_in[0];
    const float* W_enc = (const float*)d_in[1];
    const float* b_enc = (const float*)d_in[2];
    const float* W_dec = (const float*)d_in[3];
    const float* b_dec = (const float*)d_in[4];
    const float* ecs   = (const float*)d_in[5];
    const float* ep    = (const float*)d_in[6];
    float* out = (float*)d_out;

    float* ws = (float*)d_ws;
    float* wt = ws;                 // 24576 floats: W_enc transposed, k-major
    float* G  = ws + 24576;         // 576
    float* h  = ws + 25152;         // 24
    float* bb = ws + 25176;         // 1

    const int rows = in_sizes[0] / 1024;    // 32768

    hipLaunchKernelGGL(prep_all, dim3(985), dim3(64), 0, stream,
                       W_enc, W_dec, b_dec, wt, G, h, bb);
    hipLaunchKernelGGL(leech_main, dim3(rows / 64), dim3(512), 0, stream,
                       data, b_enc, W_dec, b_dec, ecs, ep, wt, G, h, bb, out);
}

// Round 6
// 312.641 us; speedup vs baseline: 1.3030x; 1.3030x over previous
//
#include <hip/hip_runtime.h>
#include <math.h>

#define EPS 1e-8f

typedef float vfloat4 __attribute__((ext_vector_type(4)));

// ---------------- prep kernel (fused transpose + Gram) ----------------
// blocks 0..383   : transpose W_enc [24][1024] -> wt [1024][24]  (64 thr each)
// blocks 384..959 : G[l][m] = sum_d Wd[d][l]*Wd[d][m]
// blocks 960..983 : h[l] = sum_d Wd[d][l]*bd[d]
// block  984      : bb = ||bd||^2
__global__ void prep_all(const float* __restrict__ W_enc,
                         const float* __restrict__ Wd, const float* __restrict__ bd,
                         float* __restrict__ wt, float* __restrict__ G,
                         float* __restrict__ h, float* __restrict__ bb) {
    int b = blockIdx.x;
    int lane = threadIdx.x;     // 64
    if (b < 384) {
        int i = b * 64 + lane;  // 0..24575
        int k = i / 24, l = i - k * 24;
        wt[i] = W_enc[l * 1024 + k];
        return;
    }
    b -= 384;
    float s = 0.f;
    if (b < 576) {
        int l = b / 24, m = b - (b / 24) * 24;
        for (int d = lane; d < 1024; d += 64) s = fmaf(Wd[d * 24 + l], Wd[d * 24 + m], s);
    } else if (b < 600) {
        int l = b - 576;
        for (int d = lane; d < 1024; d += 64) s = fmaf(Wd[d * 24 + l], bd[d], s);
    } else {
        for (int d = lane; d < 1024; d += 64) s = fmaf(bd[d], bd[d], s);
    }
    for (int off = 32; off; off >>= 1) s += __shfl_down(s, off);
    if (lane == 0) {
        if (b < 576) G[b] = s;
        else if (b < 600) h[b - 576] = s;
        else *bb = s;
    }
}

// ---------------- main kernel ----------------
// r4: 128 rows per block (was 64), grid 256 = 1 block/CU.
// Rationale: bottleneck is the compulsory scalar-cache weight stream
// (192 KB/block of wt+Wd via s_load; broadcast via SGPR operand is the only
// zero-bandwidth path — r3 proved VMEM broadcast is worse). Stream per block
// is fixed, so halve blocks/CU: 384 -> 192 KB/CU, and each s_load weight
// now feeds 2 rows (48 FMAs). Weight loads are plain scalar indexing
// (s_load, K$); r3's zz trick reverted.
// Block = 512 thr (8 waves); wave w owns k/d-slice [128w,128w+128);
// lane r owns rows r and r+64. Tiles wave-private [128][32] XOR-swizzled
// (col ^ (row&31)): reads 2-way (free), staged writes 2-way (free).
// 8 x 16 KB = 128 KiB LDS. Same-wave LDS in-order -> no barriers in chunk
// loops; exactly 2 __syncthreads around the cross-wave combine.

constexpr int BROWS   = 128;
constexpr int LD_TILE = 32;
constexpr int TILE_F  = BROWS * LD_TILE;   // 4096 floats per wave
constexpr int NW      = 8;
constexpr int SMEM_F  = NW * TILE_F;       // 32768 floats = 128 KiB

__global__ __launch_bounds__(512, 2)
void leech_main(const float* __restrict__ data,
                const float* __restrict__ b_enc,
                const float* __restrict__ Wd,
                const float* __restrict__ b_dec,
                const float* __restrict__ ecs_p,
                const float* __restrict__ ep_p,
                const float* __restrict__ wt,
                const float* __restrict__ G,
                const float* __restrict__ h,
                const float* __restrict__ bbp,
                float* __restrict__ out)
{
    __shared__ float smem[SMEM_F];
    const int tid = threadIdx.x;
    const int w = tid >> 6;         // 0..7
    const int r = tid & 63;
    const int rowbase = blockIdx.x * BROWS;

    float* tile = smem + w * TILE_F;

    const int lrow = r >> 3;        // 0..7
    const int lk   = (r & 7) * 4;   // 0,4,...,28
    const int rb   = r & 31;

    // -------- encode: proj partials over this wave's 128-wide k-range ------
    float proj0[24], proj1[24];
#pragma unroll
    for (int l = 0; l < 24; ++l) { proj0[l] = 0.f; proj1[l] = 0.f; }
    float ssq0 = 0.f, ssq1 = 0.f;

    const int kw = __builtin_amdgcn_readfirstlane((tid >> 6) * 128);

    float4 buf[16];
#pragma unroll
    for (int it = 0; it < 16; ++it)
        buf[it] = *reinterpret_cast<const float4*>(
            data + (size_t)(rowbase + it * 8 + lrow) * 1024 + kw + lk);

    for (int sc = 0; sc < 4; ++sc) {
        // stage current chunk into wave-private swizzled tile (128 rows x 32)
#pragma unroll
        for (int it = 0; it < 16; ++it) {
            const int row = it * 8 + lrow;
            const int rbw = row & 31;
            float* t = tile + row * LD_TILE;
            t[(lk + 0) ^ rbw] = buf[it].x;
            t[(lk + 1) ^ rbw] = buf[it].y;
            t[(lk + 2) ^ rbw] = buf[it].z;
            t[(lk + 3) ^ rbw] = buf[it].w;
        }
        // prefetch next chunk (issued before compute; latency hidden)
        if (sc < 3) {
            const int k0n = kw + (sc + 1) * 32;
#pragma unroll
            for (int it = 0; it < 16; ++it)
                buf[it] = *reinterpret_cast<const float4*>(
                    data + (size_t)(rowbase + it * 8 + lrow) * 1024 + k0n + lk);
        }
        // compute on current chunk (same-wave LDS in-order: no barrier)
        const float* x0 = tile + r * LD_TILE;
        const float* x1 = tile + (r + 64) * LD_TILE;   // (r+64)&31 == r&31
        const int kofs = __builtin_amdgcn_readfirstlane(kw + sc * 32);
#pragma unroll 4
        for (int kk = 0; kk < 32; ++kk) {
            const float a = x0[kk ^ rb];
            const float b = x1[kk ^ rb];
            ssq0 = fmaf(a, a, ssq0);
            ssq1 = fmaf(b, b, ssq1);
            const float* wp = wt + (size_t)(kofs + kk) * 24;   // uniform -> s_load
#pragma unroll
            for (int l = 0; l < 24; ++l) {
                const float wv = wp[l];
                proj0[l] = fmaf(wv, a, proj0[l]);
                proj1[l] = fmaf(wv, b, proj1[l]);
            }
        }
    }

    // -------- combine partials across the 8 waves (overlay own tile) -------
    // layout: i*64 + r within wave region; i = l (row0), 24+l (row1), 48/49 ssq
#pragma unroll
    for (int l = 0; l < 24; ++l) {
        smem[w * TILE_F + l * 64 + r]        = proj0[l];
        smem[w * TILE_F + (24 + l) * 64 + r] = proj1[l];
    }
    smem[w * TILE_F + 48 * 64 + r] = ssq0;
    smem[w * TILE_F + 49 * 64 + r] = ssq1;
    __syncthreads();

    float p0[24], p1[24];
#pragma unroll
    for (int l = 0; l < 24; ++l) {
        float a0 = smem[0 * TILE_F + l * 64 + r] + smem[1 * TILE_F + l * 64 + r];
        float a1 = smem[2 * TILE_F + l * 64 + r] + smem[3 * TILE_F + l * 64 + r];
        float a2 = smem[4 * TILE_F + l * 64 + r] + smem[5 * TILE_F + l * 64 + r];
        float a3 = smem[6 * TILE_F + l * 64 + r] + smem[7 * TILE_F + l * 64 + r];
        p0[l] = (a0 + a1) + (a2 + a3);
        float b0 = smem[0 * TILE_F + (24 + l) * 64 + r] + smem[1 * TILE_F + (24 + l) * 64 + r];
        float b1 = smem[2 * TILE_F + (24 + l) * 64 + r] + smem[3 * TILE_F + (24 + l) * 64 + r];
        float b2 = smem[4 * TILE_F + (24 + l) * 64 + r] + smem[5 * TILE_F + (24 + l) * 64 + r];
        float b3 = smem[6 * TILE_F + (24 + l) * 64 + r] + smem[7 * TILE_F + (24 + l) * 64 + r];
        p1[l] = (b0 + b1) + (b2 + b3);
    }
    float ss0, ss1;
    {
        float a0 = smem[0 * TILE_F + 48 * 64 + r] + smem[1 * TILE_F + 48 * 64 + r];
        float a1 = smem[2 * TILE_F + 48 * 64 + r] + smem[3 * TILE_F + 48 * 64 + r];
        float a2 = smem[4 * TILE_F + 48 * 64 + r] + smem[5 * TILE_F + 48 * 64 + r];
        float a3 = smem[6 * TILE_F + 48 * 64 + r] + smem[7 * TILE_F + 48 * 64 + r];
        ss0 = (a0 + a1) + (a2 + a3);
        float b0 = smem[0 * TILE_F + 49 * 64 + r] + smem[1 * TILE_F + 49 * 64 + r];
        float b1 = smem[2 * TILE_F + 49 * 64 + r] + smem[3 * TILE_F + 49 * 64 + r];
        float b2 = smem[4 * TILE_F + 49 * 64 + r] + smem[5 * TILE_F + 49 * 64 + r];
        float b3 = smem[6 * TILE_F + 49 * 64 + r] + smem[7 * TILE_F + 49 * 64 + r];
        ss1 = (b0 + b1) + (b2 + b3);
    }
    __syncthreads();   // all combine reads done before decode overwrites tiles

    // -------- per-row epilogue (two rows per lane) --------
    const float ecs = ecs_p[0];
    const float ep  = ep_p[0];

    float c0[24], c1[24];
    float s2a, s2b;
    {
        const float in_e = sqrtf(ss0);
        float lp[24]; float oe = 0.f;
#pragma unroll
        for (int l = 0; l < 24; ++l) {
            const float pp = p0[l] + b_enc[l];
            const float q = rintf(pp / ecs) * ecs;   // half-even, matches np
            lp[l] = q;
            oe = fmaf(q, q, oe);
        }
        const float s1 = in_e / (sqrtf(oe) + EPS) * ep;
        float ie = 0.f;
#pragma unroll
        for (int l = 0; l < 24; ++l) {
            const float lat = lp[l] * s1;
            ie = fmaf(lat, lat, ie);
            c0[l] = (fabsf(lat) > ecs) ? lat : 0.f;
        }
        const float in_e2 = sqrtf(ie);
        float qacc = bbp[0];
#pragma unroll
        for (int l = 0; l < 24; ++l) {
            float s = 2.f * h[l];
#pragma unroll
            for (int m = 0; m < 24; ++m)
                s = fmaf(G[l * 24 + m], c0[m], s);
            qacc = fmaf(s, c0[l], qacc);
        }
        const float out_e2 = sqrtf(fmaxf(qacc, 0.f));
        s2a = in_e2 / (out_e2 + EPS) * ep;
    }
    {
        const float in_e = sqrtf(ss1);
        float lp[24]; float oe = 0.f;
#pragma unroll
        for (int l = 0; l < 24; ++l) {
            const float pp = p1[l] + b_enc[l];
            const float q = rintf(pp / ecs) * ecs;
            lp[l] = q;
            oe = fmaf(q, q, oe);
        }
        const float s1 = in_e / (sqrtf(oe) + EPS) * ep;
        float ie = 0.f;
#pragma unroll
        for (int l = 0; l < 24; ++l) {
            const float lat = lp[l] * s1;
            ie = fmaf(lat, lat, ie);
            c1[l] = (fabsf(lat) > ecs) ? lat : 0.f;
        }
        const float in_e2 = sqrtf(ie);
        float qacc = bbp[0];
#pragma unroll
        for (int l = 0; l < 24; ++l) {
            float s = 2.f * h[l];
#pragma unroll
            for (int m = 0; m < 24; ++m)
                s = fmaf(G[l * 24 + m], c1[m], s);
            qacc = fmaf(s, c1[l], qacc);
        }
        const float out_e2 = sqrtf(fmaxf(qacc, 0.f));
        s2b = in_e2 / (out_e2 + EPS) * ep;
    }

    // -------- decode: wave-private swizzled transpose tiles, no barriers ---
    for (int sc = 0; sc < 4; ++sc) {
        const int d0 = __builtin_amdgcn_readfirstlane(kw + sc * 32);
        float* t0 = tile + r * LD_TILE;
        float* t1 = tile + (r + 64) * LD_TILE;
#pragma unroll 4
        for (int dd = 0; dd < 32; ++dd) {
            const int d = d0 + dd;
            const float* wr = Wd + d * 24;       // uniform -> s_load
            const float bv = b_dec[d];
            float acc0 = bv, acc1 = bv;
#pragma unroll
            for (int l = 0; l < 24; ++l) {
                const float wv = wr[l];
                acc0 = fmaf(wv, c0[l], acc0);
                acc1 = fmaf(wv, c1[l], acc1);
            }
            t0[dd ^ rb] = acc0 * s2a;
            t1[dd ^ rb] = acc1 * s2b;
        }
        // same-wave LDS in-order: reads below see this wave's writes above
#pragma unroll
        for (int it = 0; it < 16; ++it) {
            const int row = it * 8 + lrow;
            const int rbw = row & 31;
            const float* t = tile + row * LD_TILE;
            vfloat4 v;
            v.x = t[(lk + 0) ^ rbw];
            v.y = t[(lk + 1) ^ rbw];
            v.z = t[(lk + 2) ^ rbw];
            v.w = t[(lk + 3) ^ rbw];
            __builtin_nontemporal_store(v, reinterpret_cast<vfloat4*>(
                out + (size_t)(rowbase + row) * 1024 + d0 + lk));
        }
    }
}

// ---------------- launcher ----------------

extern "C" void kernel_launch(void* const* d_in, const int* in_sizes, int n_in,
                              void* d_out, int out_size, void* d_ws, size_t ws_size,
                              hipStream_t stream) {
    const float* data  = (const float*)d_in[0];
    const float* W_enc = (const float*)d_in[1];
    const float* b_enc = (const float*)d_in[2];
    const float* W_dec = (const float*)d_in[3];
    const float* b_dec = (const float*)d_in[4];
    const float* ecs   = (const float*)d_in[5];
    const float* ep    = (const float*)d_in[6];
    float* out = (float*)d_out;

    float* ws = (float*)d_ws;
    float* wt = ws;                 // 24576 floats: W_enc transposed, k-major
    float* G  = ws + 24576;         // 576
    float* h  = ws + 25152;         // 24
    float* bb = ws + 25176;         // 1

    const int rows = in_sizes[0] / 1024;    // 32768

    hipLaunchKernelGGL(prep_all, dim3(985), dim3(64), 0, stream,
                       W_enc, W_dec, b_dec, wt, G, h, bb);
    hipLaunchKernelGGL(leech_main, dim3(rows / BROWS), dim3(512), 0, stream,
                       data, b_enc, W_dec, b_dec, ecs, ep, wt, G, h, bb, out);
}

// Round 7
// 292.659 us; speedup vs baseline: 1.3919x; 1.0683x over previous
//
#include <hip/hip_runtime.h>
#include <math.h>

#define EPS 1e-8f

typedef float vfloat4 __attribute__((ext_vector_type(4)));

// ---------------- prep kernel (fused transpose + Gram) ----------------
// blocks 0..383   : transpose W_enc [24][1024] -> wt [1024][24]  (64 thr each)
// blocks 384..959 : G[l][m] = sum_d Wd[d][l]*Wd[d][m]
// blocks 960..983 : h[l] = sum_d Wd[d][l]*bd[d]
// block  984      : bb = ||bd||^2
__global__ void prep_all(const float* __restrict__ W_enc,
                         const float* __restrict__ Wd, const float* __restrict__ bd,
                         float* __restrict__ wt, float* __restrict__ G,
                         float* __restrict__ h, float* __restrict__ bb) {
    int b = blockIdx.x;
    int lane = threadIdx.x;     // 64
    if (b < 384) {
        int i = b * 64 + lane;  // 0..24575
        int k = i / 24, l = i - k * 24;
        wt[i] = W_enc[l * 1024 + k];
        return;
    }
    b -= 384;
    float s = 0.f;
    if (b < 576) {
        int l = b / 24, m = b - (b / 24) * 24;
        for (int d = lane; d < 1024; d += 64) s = fmaf(Wd[d * 24 + l], Wd[d * 24 + m], s);
    } else if (b < 600) {
        int l = b - 576;
        for (int d = lane; d < 1024; d += 64) s = fmaf(Wd[d * 24 + l], bd[d], s);
    } else {
        for (int d = lane; d < 1024; d += 64) s = fmaf(bd[d], bd[d], s);
    }
    for (int off = 32; off; off >>= 1) s += __shfl_down(s, off);
    if (lane == 0) {
        if (b < 576) G[b] = s;
        else if (b < 600) h[b - 576] = s;
        else *bb = s;
    }
}

// ---------------- main kernel ----------------
// r6 CHANGE: weights come from LDS (wave-uniform ds_read_b128 broadcast),
// not s_load. Rationale: r4 falsified SQC *bandwidth* (halving the stream
// gave 7%, not 2x). Remaining suspect: s_load (out-of-order) + ds_read
// (in-order) share lgkmcnt -> compiler must drain lgkmcnt(0) every unroll
// group; ~200cy scalar latency exposed ~256x/wave, and SGPR budget caps
// pipelining at ~3 rows. Pure-DS hot loops get counted lgkmcnt(N) waits
// -> weight reads pipeline under FMAs.
// Per chunk each wave stages its own 32x24 weight slice (3 KB) into a
// wave-private LDS region (same-wave DS in-order -> no barrier), plus the
// b_dec chunk for decode. FMA order unchanged -> bit-identical output.
// Block = 512 thr (8 waves); 128 rows/block; grid 256 = 1 block/CU.
// Lane r owns rows r and r+64. Tiles wave-private [128][32] XOR-swizzled.
// LDS: 8x16KB tiles + 8x3.2KB weight regions = 153 KB.

constexpr int BROWS   = 128;
constexpr int LD_TILE = 32;
constexpr int TILE_F  = BROWS * LD_TILE;   // 4096 floats per wave
constexpr int NW      = 8;
constexpr int WREG_F  = 800;               // 768 weights + 32 bias
constexpr int SMEM_F  = NW * TILE_F + NW * WREG_F;  // 39168 floats = 153 KiB

__global__ __launch_bounds__(512, 2)
void leech_main(const float* __restrict__ data,
                const float* __restrict__ b_enc,
                const float* __restrict__ Wd,
                const float* __restrict__ b_dec,
                const float* __restrict__ ecs_p,
                const float* __restrict__ ep_p,
                const float* __restrict__ wt,
                const float* __restrict__ G,
                const float* __restrict__ h,
                const float* __restrict__ bbp,
                float* __restrict__ out)
{
    __shared__ float smem[SMEM_F];
    const int tid = threadIdx.x;
    const int w = tid >> 6;         // 0..7
    const int r = tid & 63;
    const int rowbase = blockIdx.x * BROWS;

    float* tile = smem + w * TILE_F;
    float* wreg = smem + NW * TILE_F + w * WREG_F;   // wave-private weights

    const int lrow = r >> 3;        // 0..7
    const int lk   = (r & 7) * 4;   // 0,4,...,28
    const int rb   = r & 31;

    // -------- encode: proj partials over this wave's 128-wide k-range ------
    float proj0[24], proj1[24];
#pragma unroll
    for (int l = 0; l < 24; ++l) { proj0[l] = 0.f; proj1[l] = 0.f; }
    float ssq0 = 0.f, ssq1 = 0.f;

    const int kw = __builtin_amdgcn_readfirstlane((tid >> 6) * 128);

    float4 buf[16];
#pragma unroll
    for (int it = 0; it < 16; ++it)
        buf[it] = *reinterpret_cast<const float4*>(
            data + (size_t)(rowbase + it * 8 + lrow) * 1024 + kw + lk);

    for (int sc = 0; sc < 4; ++sc) {
        const int kofs = __builtin_amdgcn_readfirstlane(kw + sc * 32);
        // stage this chunk's weights (wave-private; same-wave DS in-order)
        {
            const float* gsrc = wt + (size_t)kofs * 24 + r * 12;  // 64*12=768
            float4 wa = *reinterpret_cast<const float4*>(gsrc);
            float4 wb = *reinterpret_cast<const float4*>(gsrc + 4);
            float4 wc = *reinterpret_cast<const float4*>(gsrc + 8);
            float* dst = wreg + r * 12;
            *reinterpret_cast<float4*>(dst)     = wa;
            *reinterpret_cast<float4*>(dst + 4) = wb;
            *reinterpret_cast<float4*>(dst + 8) = wc;
        }
        // stage current data chunk into wave-private swizzled tile
#pragma unroll
        for (int it = 0; it < 16; ++it) {
            const int row = it * 8 + lrow;
            const int rbw = row & 31;
            float* t = tile + row * LD_TILE;
            t[(lk + 0) ^ rbw] = buf[it].x;
            t[(lk + 1) ^ rbw] = buf[it].y;
            t[(lk + 2) ^ rbw] = buf[it].z;
            t[(lk + 3) ^ rbw] = buf[it].w;
        }
        // prefetch next chunk (issued before compute; latency hidden)
        if (sc < 3) {
            const int k0n = kw + (sc + 1) * 32;
#pragma unroll
            for (int it = 0; it < 16; ++it)
                buf[it] = *reinterpret_cast<const float4*>(
                    data + (size_t)(rowbase + it * 8 + lrow) * 1024 + k0n + lk);
        }
        // compute on current chunk (pure-DS: counted lgkmcnt, no s_load)
        const float* x0 = tile + r * LD_TILE;
        const float* x1 = tile + (r + 64) * LD_TILE;   // (r+64)&31 == r&31
#pragma unroll 4
        for (int kk = 0; kk < 32; ++kk) {
            const float a = x0[kk ^ rb];
            const float b = x1[kk ^ rb];
            ssq0 = fmaf(a, a, ssq0);
            ssq1 = fmaf(b, b, ssq1);
            const float* wrow = wreg + kk * 24;   // uniform -> ds broadcast
            const vfloat4 w0 = *reinterpret_cast<const vfloat4*>(wrow);
            const vfloat4 w1 = *reinterpret_cast<const vfloat4*>(wrow + 4);
            const vfloat4 w2 = *reinterpret_cast<const vfloat4*>(wrow + 8);
            const vfloat4 w3 = *reinterpret_cast<const vfloat4*>(wrow + 12);
            const vfloat4 w4 = *reinterpret_cast<const vfloat4*>(wrow + 16);
            const vfloat4 w5 = *reinterpret_cast<const vfloat4*>(wrow + 20);
            proj0[ 0] = fmaf(w0.x, a, proj0[ 0]);  proj1[ 0] = fmaf(w0.x, b, proj1[ 0]);
            proj0[ 1] = fmaf(w0.y, a, proj0[ 1]);  proj1[ 1] = fmaf(w0.y, b, proj1[ 1]);
            proj0[ 2] = fmaf(w0.z, a, proj0[ 2]);  proj1[ 2] = fmaf(w0.z, b, proj1[ 2]);
            proj0[ 3] = fmaf(w0.w, a, proj0[ 3]);  proj1[ 3] = fmaf(w0.w, b, proj1[ 3]);
            proj0[ 4] = fmaf(w1.x, a, proj0[ 4]);  proj1[ 4] = fmaf(w1.x, b, proj1[ 4]);
            proj0[ 5] = fmaf(w1.y, a, proj0[ 5]);  proj1[ 5] = fmaf(w1.y, b, proj1[ 5]);
            proj0[ 6] = fmaf(w1.z, a, proj0[ 6]);  proj1[ 6] = fmaf(w1.z, b, proj1[ 6]);
            proj0[ 7] = fmaf(w1.w, a, proj0[ 7]);  proj1[ 7] = fmaf(w1.w, b, proj1[ 7]);
            proj0[ 8] = fmaf(w2.x, a, proj0[ 8]);  proj1[ 8] = fmaf(w2.x, b, proj1[ 8]);
            proj0[ 9] = fmaf(w2.y, a, proj0[ 9]);  proj1[ 9] = fmaf(w2.y, b, proj1[ 9]);
            proj0[10] = fmaf(w2.z, a, proj0[10]);  proj1[10] = fmaf(w2.z, b, proj1[10]);
            proj0[11] = fmaf(w2.w, a, proj0[11]);  proj1[11] = fmaf(w2.w, b, proj1[11]);
            proj0[12] = fmaf(w3.x, a, proj0[12]);  proj1[12] = fmaf(w3.x, b, proj1[12]);
            proj0[13] = fmaf(w3.y, a, proj0[13]);  proj1[13] = fmaf(w3.y, b, proj1[13]);
            proj0[14] = fmaf(w3.z, a, proj0[14]);  proj1[14] = fmaf(w3.z, b, proj1[14]);
            proj0[15] = fmaf(w3.w, a, proj0[15]);  proj1[15] = fmaf(w3.w, b, proj1[15]);
            proj0[16] = fmaf(w4.x, a, proj0[16]);  proj1[16] = fmaf(w4.x, b, proj1[16]);
            proj0[17] = fmaf(w4.y, a, proj0[17]);  proj1[17] = fmaf(w4.y, b, proj1[17]);
            proj0[18] = fmaf(w4.z, a, proj0[18]);  proj1[18] = fmaf(w4.z, b, proj1[18]);
            proj0[19] = fmaf(w4.w, a, proj0[19]);  proj1[19] = fmaf(w4.w, b, proj1[19]);
            proj0[20] = fmaf(w5.x, a, proj0[20]);  proj1[20] = fmaf(w5.x, b, proj1[20]);
            proj0[21] = fmaf(w5.y, a, proj0[21]);  proj1[21] = fmaf(w5.y, b, proj1[21]);
            proj0[22] = fmaf(w5.z, a, proj0[22]);  proj1[22] = fmaf(w5.z, b, proj1[22]);
            proj0[23] = fmaf(w5.w, a, proj0[23]);  proj1[23] = fmaf(w5.w, b, proj1[23]);
        }
    }

    // -------- combine partials across the 8 waves (overlay own tile) -------
#pragma unroll
    for (int l = 0; l < 24; ++l) {
        smem[w * TILE_F + l * 64 + r]        = proj0[l];
        smem[w * TILE_F + (24 + l) * 64 + r] = proj1[l];
    }
    smem[w * TILE_F + 48 * 64 + r] = ssq0;
    smem[w * TILE_F + 49 * 64 + r] = ssq1;
    __syncthreads();

    float p0[24], p1[24];
#pragma unroll
    for (int l = 0; l < 24; ++l) {
        float a0 = smem[0 * TILE_F + l * 64 + r] + smem[1 * TILE_F + l * 64 + r];
        float a1 = smem[2 * TILE_F + l * 64 + r] + smem[3 * TILE_F + l * 64 + r];
        float a2 = smem[4 * TILE_F + l * 64 + r] + smem[5 * TILE_F + l * 64 + r];
        float a3 = smem[6 * TILE_F + l * 64 + r] + smem[7 * TILE_F + l * 64 + r];
        p0[l] = (a0 + a1) + (a2 + a3);
        float b0 = smem[0 * TILE_F + (24 + l) * 64 + r] + smem[1 * TILE_F + (24 + l) * 64 + r];
        float b1 = smem[2 * TILE_F + (24 + l) * 64 + r] + smem[3 * TILE_F + (24 + l) * 64 + r];
        float b2 = smem[4 * TILE_F + (24 + l) * 64 + r] + smem[5 * TILE_F + (24 + l) * 64 + r];
        float b3 = smem[6 * TILE_F + (24 + l) * 64 + r] + smem[7 * TILE_F + (24 + l) * 64 + r];
        p1[l] = (b0 + b1) + (b2 + b3);
    }
    float ss0, ss1;
    {
        float a0 = smem[0 * TILE_F + 48 * 64 + r] + smem[1 * TILE_F + 48 * 64 + r];
        float a1 = smem[2 * TILE_F + 48 * 64 + r] + smem[3 * TILE_F + 48 * 64 + r];
        float a2 = smem[4 * TILE_F + 48 * 64 + r] + smem[5 * TILE_F + 48 * 64 + r];
        float a3 = smem[6 * TILE_F + 48 * 64 + r] + smem[7 * TILE_F + 48 * 64 + r];
        ss0 = (a0 + a1) + (a2 + a3);
        float b0 = smem[0 * TILE_F + 49 * 64 + r] + smem[1 * TILE_F + 49 * 64 + r];
        float b1 = smem[2 * TILE_F + 49 * 64 + r] + smem[3 * TILE_F + 49 * 64 + r];
        float b2 = smem[4 * TILE_F + 49 * 64 + r] + smem[5 * TILE_F + 49 * 64 + r];
        float b3 = smem[6 * TILE_F + 49 * 64 + r] + smem[7 * TILE_F + 49 * 64 + r];
        ss1 = (b0 + b1) + (b2 + b3);
    }
    __syncthreads();   // all combine reads done before decode overwrites tiles

    // -------- per-row epilogue (two rows per lane) --------
    const float ecs = ecs_p[0];
    const float ep  = ep_p[0];

    float c0[24], c1[24];
    float s2a, s2b;
    {
        const float in_e = sqrtf(ss0);
        float lp[24]; float oe = 0.f;
#pragma unroll
        for (int l = 0; l < 24; ++l) {
            const float pp = p0[l] + b_enc[l];
            const float q = rintf(pp / ecs) * ecs;   // half-even, matches np
            lp[l] = q;
            oe = fmaf(q, q, oe);
        }
        const float s1 = in_e / (sqrtf(oe) + EPS) * ep;
        float ie = 0.f;
#pragma unroll
        for (int l = 0; l < 24; ++l) {
            const float lat = lp[l] * s1;
            ie = fmaf(lat, lat, ie);
            c0[l] = (fabsf(lat) > ecs) ? lat : 0.f;
        }
        const float in_e2 = sqrtf(ie);
        float qacc = bbp[0];
#pragma unroll
        for (int l = 0; l < 24; ++l) {
            float s = 2.f * h[l];
#pragma unroll
            for (int m = 0; m < 24; ++m)
                s = fmaf(G[l * 24 + m], c0[m], s);
            qacc = fmaf(s, c0[l], qacc);
        }
        const float out_e2 = sqrtf(fmaxf(qacc, 0.f));
        s2a = in_e2 / (out_e2 + EPS) * ep;
    }
    {
        const float in_e = sqrtf(ss1);
        float lp[24]; float oe = 0.f;
#pragma unroll
        for (int l = 0; l < 24; ++l) {
            const float pp = p1[l] + b_enc[l];
            const float q = rintf(pp / ecs) * ecs;
            lp[l] = q;
            oe = fmaf(q, q, oe);
        }
        const float s1 = in_e / (sqrtf(oe) + EPS) * ep;
        float ie = 0.f;
#pragma unroll
        for (int l = 0; l < 24; ++l) {
            const float lat = lp[l] * s1;
            ie = fmaf(lat, lat, ie);
            c1[l] = (fabsf(lat) > ecs) ? lat : 0.f;
        }
        const float in_e2 = sqrtf(ie);
        float qacc = bbp[0];
#pragma unroll
        for (int l = 0; l < 24; ++l) {
            float s = 2.f * h[l];
#pragma unroll
            for (int m = 0; m < 24; ++m)
                s = fmaf(G[l * 24 + m], c1[m], s);
            qacc = fmaf(s, c1[l], qacc);
        }
        const float out_e2 = sqrtf(fmaxf(qacc, 0.f));
        s2b = in_e2 / (out_e2 + EPS) * ep;
    }

    // -------- decode: wave-private swizzled transpose tiles, no barriers ---
    for (int sc = 0; sc < 4; ++sc) {
        const int d0 = __builtin_amdgcn_readfirstlane(kw + sc * 32);
        // stage this chunk's decode weights + bias (wave-private)
        {
            const float* gsrc = Wd + (size_t)d0 * 24 + r * 12;
            float4 wa = *reinterpret_cast<const float4*>(gsrc);
            float4 wb = *reinterpret_cast<const float4*>(gsrc + 4);
            float4 wc = *reinterpret_cast<const float4*>(gsrc + 8);
            float* dst = wreg + r * 12;
            *reinterpret_cast<float4*>(dst)     = wa;
            *reinterpret_cast<float4*>(dst + 4) = wb;
            *reinterpret_cast<float4*>(dst + 8) = wc;
            if (r < 8) {
                float4 bv = *reinterpret_cast<const float4*>(b_dec + d0 + r * 4);
                *reinterpret_cast<float4*>(wreg + 768 + r * 4) = bv;
            }
        }
        float* t0 = tile + r * LD_TILE;
        float* t1 = tile + (r + 64) * LD_TILE;
#pragma unroll 4
        for (int dd = 0; dd < 32; ++dd) {
            const float* wrow = wreg + dd * 24;   // uniform -> ds broadcast
            const vfloat4 w0 = *reinterpret_cast<const vfloat4*>(wrow);
            const vfloat4 w1 = *reinterpret_cast<const vfloat4*>(wrow + 4);
            const vfloat4 w2 = *reinterpret_cast<const vfloat4*>(wrow + 8);
            const vfloat4 w3 = *reinterpret_cast<const vfloat4*>(wrow + 12);
            const vfloat4 w4 = *reinterpret_cast<const vfloat4*>(wrow + 16);
            const vfloat4 w5 = *reinterpret_cast<const vfloat4*>(wrow + 20);
            const float bv = wreg[768 + dd];
            float acc0 = bv, acc1 = bv;
            acc0 = fmaf(w0.x, c0[ 0], acc0);  acc1 = fmaf(w0.x, c1[ 0], acc1);
            acc0 = fmaf(w0.y, c0[ 1], acc0);  acc1 = fmaf(w0.y, c1[ 1], acc1);
            acc0 = fmaf(w0.z, c0[ 2], acc0);  acc1 = fmaf(w0.z, c1[ 2], acc1);
            acc0 = fmaf(w0.w, c0[ 3], acc0);  acc1 = fmaf(w0.w, c1[ 3], acc1);
            acc0 = fmaf(w1.x, c0[ 4], acc0);  acc1 = fmaf(w1.x, c1[ 4], acc1);
            acc0 = fmaf(w1.y, c0[ 5], acc0);  acc1 = fmaf(w1.y, c1[ 5], acc1);
            acc0 = fmaf(w1.z, c0[ 6], acc0);  acc1 = fmaf(w1.z, c1[ 6], acc1);
            acc0 = fmaf(w1.w, c0[ 7], acc0);  acc1 = fmaf(w1.w, c1[ 7], acc1);
            acc0 = fmaf(w2.x, c0[ 8], acc0);  acc1 = fmaf(w2.x, c1[ 8], acc1);
            acc0 = fmaf(w2.y, c0[ 9], acc0);  acc1 = fmaf(w2.y, c1[ 9], acc1);
            acc0 = fmaf(w2.z, c0[10], acc0);  acc1 = fmaf(w2.z, c1[10], acc1);
            acc0 = fmaf(w2.w, c0[11], acc0);  acc1 = fmaf(w2.w, c1[11], acc1);
            acc0 = fmaf(w3.x, c0[12], acc0);  acc1 = fmaf(w3.x, c1[12], acc1);
            acc0 = fmaf(w3.y, c0[13], acc0);  acc1 = fmaf(w3.y, c1[13], acc1);
            acc0 = fmaf(w3.z, c0[14], acc0);  acc1 = fmaf(w3.z, c1[14], acc1);
            acc0 = fmaf(w3.w, c0[15], acc0);  acc1 = fmaf(w3.w, c1[15], acc1);
            acc0 = fmaf(w4.x, c0[16], acc0);  acc1 = fmaf(w4.x, c1[16], acc1);
            acc0 = fmaf(w4.y, c0[17], acc0);  acc1 = fmaf(w4.y, c1[17], acc1);
            acc0 = fmaf(w4.z, c0[18], acc0);  acc1 = fmaf(w4.z, c1[18], acc1);
            acc0 = fmaf(w4.w, c0[19], acc0);  acc1 = fmaf(w4.w, c1[19], acc1);
            acc0 = fmaf(w5.x, c0[20], acc0);  acc1 = fmaf(w5.x, c1[20], acc1);
            acc0 = fmaf(w5.y, c0[21], acc0);  acc1 = fmaf(w5.y, c1[21], acc1);
            acc0 = fmaf(w5.z, c0[22], acc0);  acc1 = fmaf(w5.z, c1[22], acc1);
            acc0 = fmaf(w5.w, c0[23], acc0);  acc1 = fmaf(w5.w, c1[23], acc1);
            t0[dd ^ rb] = acc0 * s2a;
            t1[dd ^ rb] = acc1 * s2b;
        }
        // same-wave LDS in-order: reads below see this wave's writes above
#pragma unroll
        for (int it = 0; it < 16; ++it) {
            const int row = it * 8 + lrow;
            const int rbw = row & 31;
            const float* t = tile + row * LD_TILE;
            vfloat4 v;
            v.x = t[(lk + 0) ^ rbw];
            v.y = t[(lk + 1) ^ rbw];
            v.z = t[(lk + 2) ^ rbw];
            v.w = t[(lk + 3) ^ rbw];
            __builtin_nontemporal_store(v, reinterpret_cast<vfloat4*>(
                out + (size_t)(rowbase + row) * 1024 + d0 + lk));
        }
    }
}

// ---------------- launcher ----------------

extern "C" void kernel_launch(void* const* d_in, const int* in_sizes, int n_in,
                              void* d_out, int out_size, void* d_ws, size_t ws_size,
                              hipStream_t stream) {
    const float* data  = (const float*)d_in[0];
    const float* W_enc = (const float*)d_in[1];
    const float* b_enc = (const float*)d_in[2];
    const float* W_dec = (const float*)d_in[3];
    const float* b_dec = (const float*)d_in[4];
    const float* ecs   = (const float*)d_in[5];
    const float* ep    = (const float*)d_in[6];
    float* out = (float*)d_out;

    float* ws = (float*)d_ws;
    float* wt = ws;                 // 24576 floats: W_enc transposed, k-major
    float* G  = ws + 24576;         // 576
    float* h  = ws + 25152;         // 24
    float* bb = ws + 25176;         // 1

    const int rows = in_sizes[0] / 1024;    // 32768

    hipLaunchKernelGGL(prep_all, dim3(985), dim3(64), 0, stream,
                       W_enc, W_dec, b_dec, wt, G, h, bb);
    hipLaunchKernelGGL(leech_main, dim3(rows / BROWS), dim3(512), 0, stream,
                       data, b_enc, W_dec, b_dec, ecs, ep, wt, G, h, bb, out);
}